// Round 15
// baseline (96.567 us; speedup 1.0000x reference)
//
#include <hip/hip_runtime.h>
#include <hip/hip_bf16.h>

// RBF kernel layer: out[n][m] = exp(-||x_n - c_m||^2)
// N=16384, M=4096, D=512, fp32 in/out.
// Round 15: r14 (BK=128 persistent dual-bank fp8 GEMM, 93.2us) with the
// block sweep doubled: 256 blocks (exactly 1/CU), each sweeps 8 c-blocks
// (32 K-tiles) -> ONE prologue + ONE tail per CU instead of two, no serial
// second block generation. KT schedule is a strict periodic extension of
// r14's audited pattern (steady tiles == r14 V4-13; last two == r14
// V14/V15). vmcnt: V0-3: 4, V4-29: 8, V30: 4, V31: none.
//
// LDS 96KB: X[2][128][128B] @0/16384; C[2][256][128B] @32768/65536.
// Swizzle: LDS[row][slot] holds global 16B chunk g = slot ^ (row&7);
// read chunk fq at slot fq^(fr&7) (sxa), chunk fq|4 at (fq|4)^(fr&7) (sxb).
// Staging: linear dest (thread t -> row t>>3, slot t&7), source chunk
// (t&7)^((t>>3)&7). All LDS reads are direct typed derefs (r13 lesson:
// pointer->int->pointer round-trips defeat addrspace inference -> flat
// loads -> corrupt BOTH waitcnt domains).

#define NN 16384
#define MM 4096
#define DD 512

typedef float f32x4 __attribute__((ext_vector_type(4)));
typedef long i64x2 __attribute__((ext_vector_type(2)));

__device__ __forceinline__ void async16(const void* g, void* l) {
  __builtin_amdgcn_global_load_lds(
      (const __attribute__((address_space(1))) void*)g,
      (__attribute__((address_space(3))) void*)l, 16, 0, 0);
}

#define MFMA8(a, b, c) __builtin_amdgcn_mfma_f32_16x16x32_fp8_fp8(a, b, c, 0, 0, 0)
#define WAITVM(n) asm volatile("s_waitcnt vmcnt(" #n ")" ::: "memory")
#define LGKM0 asm volatile("s_waitcnt lgkmcnt(0)" ::: "memory")
#define BAR __builtin_amdgcn_s_barrier()
#define GLD4(dst, addr) \
  asm volatile("global_load_dwordx4 %0, %1, off" : "=v"(dst) : "v"(addr))
#define GLD1(dst, addr) \
  asm volatile("global_load_dword %0, %1, off" : "=v"(dst) : "v"(addr))

// ---------------------------------------------------------------------------
// Prep: fp32 row -> fp8 e4m3 (row bytes packed (kt, fq)-major: byte =
// kt*64 + fq*16 + ks*8 + e for element k = kt*64 + ks*32 + fq*8 + e) +
// exact fp32 squared norm. One wave per row.
// ---------------------------------------------------------------------------
__global__ __launch_bounds__(256) void prep_fp8(
    const float* __restrict__ x, const float* __restrict__ c,
    unsigned char* __restrict__ x8, unsigned char* __restrict__ c8,
    float* __restrict__ xsq, float* __restrict__ csq) {
  const int w = threadIdx.x >> 6;
  const int lane = threadIdx.x & 63;
  int row = blockIdx.x * 4 + w;
  const float* src = x;
  unsigned char* dst = x8;
  float* sq = xsq;
  if (row >= NN) {
    row -= NN;
    src = c; dst = c8; sq = csq;
    if (row >= MM) return;
  }
  const float* p = src + (size_t)row * DD + lane * 8;
  float4 v0 = *(const float4*)p;
  float4 v1 = *(const float4*)(p + 4);
  float vv[8] = {v0.x, v0.y, v0.z, v0.w, v1.x, v1.y, v1.z, v1.w};
  float s = 0.f;
#pragma unroll
  for (int j = 0; j < 8; ++j) s += vv[j] * vv[j];
  int pk0 = __builtin_amdgcn_cvt_pk_fp8_f32(vv[0], vv[1], 0, false);
  int pk1 = __builtin_amdgcn_cvt_pk_fp8_f32(vv[2], vv[3], 0, false);
  int pk2 = __builtin_amdgcn_cvt_pk_fp8_f32(vv[4], vv[5], 0, false);
  int pk3 = __builtin_amdgcn_cvt_pk_fp8_f32(vv[6], vv[7], 0, false);
  uint2 wrd;
  wrd.x = (unsigned)(pk0 & 0xFFFF) | ((unsigned)pk1 << 16);
  wrd.y = (unsigned)(pk2 & 0xFFFF) | ((unsigned)pk3 << 16);
  const int db = ((lane >> 3) << 6) + ((lane & 3) << 4) + (((lane >> 2) & 1) << 3);
  *(uint2*)(dst + (size_t)row * DD + db) = wrd;
#pragma unroll
  for (int o = 32; o >= 1; o >>= 1) s += __shfl_down(s, o);
  if (lane == 0) sq[row] = s;
}

// ---------------------------------------------------------------------------
// Persistent GEMM. 256 blocks = 128 x-panels (BM=128) x 2 strips of 8
// c-blocks; 8 waves; per wave 64 x-rows (wr) x 64 c-cols (wc) = 4x4 16x16
// frags; A=centroid, B=x (lane: x-row = fr, c-cols = fq*4+reg).
// Dual acc banks alternate per output tile (ot = V>>2, V = 0..31); old
// bank exp'd + stored (grouped 4-frag bursts) inside the next ot's K-loop.
// ---------------------------------------------------------------------------
__global__ __launch_bounds__(512, 1) void rbf_gemm(
    const unsigned char* __restrict__ x8, const unsigned char* __restrict__ c8,
    const float* __restrict__ xsq, const float* __restrict__ csq,
    float* __restrict__ out) {
  __shared__ __attribute__((aligned(16))) unsigned char smem[98304];

  const int t = threadIdx.x;
  const int w = t >> 6;
  const int lane = t & 63;
  const int fr = lane & 15;
  const int fq = lane >> 4;
  const int wr = w >> 2;
  const int wc = w & 3;

  // 256 blocks: XCD a = bid&7 (32 blocks/XCD = 1/CU); panel = a*16 + (q>>1),
  // strip = q&1 (8 c-blocks each).
  const int bid = blockIdx.x;
  const int a = bid & 7, qq = bid >> 3;
  const int x0 = ((a << 4) + (qq >> 1)) << 7;
  const int strip = qq & 1;

  // staging: thread t -> row t>>3 of 64-row issue, inverse-swizzled slot
  const int srow = t >> 3;
  const int ssl = ((t & 7) ^ ((t >> 3) & 7)) << 4;
  const unsigned char* gx = x8 + (size_t)(x0 + srow) * DD + ssl;
  const unsigned char* gc = c8 + (size_t)srow * DD + ssl;

#define XOFF(v, i) ((size_t)(i)*64 * DD + ((v)&3) * 128)
#define COFF(v, i)                                                   \
  ((size_t)(((((strip) << 3) + ((v) >> 2)) << 8) + (i)*64) * DD +    \
   ((v)&3) * 128)
#define CPI(i) (((strip << 3) + (i)) << 8)

  // ds_read slot offsets: chunk fq (kt0) at sxa, chunk fq|4 (kt1) at sxb
  const int sxa = (fq ^ (fr & 7)) << 4;
  const int sxb = ((fq | 4) ^ (fr & 7)) << 4;
  const int rowC = (wc * 64 + fr) * 128;
  const int rowX = (wr * 64 + fr) * 128;
  const int rcb = rowC + sxa, rcbB = rowC + sxb;   // + n*2048
  const int rxb = rowX + sxa, rxbB = rowX + sxb;   // + m*2048

  f32x4 aA[4][4], aB[4][4];
  f32x4 csX[4], csY[4];
  float xsr[4];

#define RD(base, off) (*(const i64x2*)((base) + (off)))

// one m-group: 4 n x 4 k-slices = 16 MFMAs. Zero-init acc at ot start.
#define MF16(AN, M, XA, XB, V)                                            \
  do {                                                                    \
    _Pragma("unroll") for (int _n = 0; _n < 4; ++_n) {                    \
      f32x4 _c = ((V)&3) == 0 ? (f32x4){0.f, 0.f, 0.f, 0.f} : AN[M][_n];  \
      _c = MFMA8(cfA[_n][0], XA[0], _c);                                  \
      _c = MFMA8(cfA[_n][1], XA[1], _c);                                  \
      _c = MFMA8(cfB[_n][0], XB[0], _c);                                  \
      AN[M][_n] = MFMA8(cfB[_n][1], XB[1], _c);                           \
    }                                                                     \
  } while (0)

// grouped store: 4 n-frags of m-group M, back-to-back (line merge)
#define STFRAG4(AO, M, CSU, CPREO)                                          \
  do {                                                                      \
    const float _xn = xsr[M] * -1.4426950408889634f;                        \
    float* _orow =                                                          \
        out + (size_t)(x0 + wr * 64 + (M)*16 + fr) * MM + (CPREO) +         \
        wc * 64 + (fq << 2);                                                \
    _Pragma("unroll") for (int _n = 0; _n < 4; ++_n) {                      \
      f32x4 _v;                                                             \
      _Pragma("unroll") for (int _j = 0; _j < 4; ++_j) {                    \
        float _arg = __builtin_fmaf(                                        \
            AO[M][_n][_j], 2.8853900817779268f,                             \
            __builtin_fmaf(CSU[_n][_j], -1.4426950408889634f, _xn));        \
        _v[_j] = fminf(__builtin_exp2f(_arg), 1.0f);                        \
      }                                                                     \
      *(f32x4*)(_orow + _n * 16) = _v;                                      \
    }                                                                       \
  } while (0)

#define KT(V, AN, AO, SEN, CPREO, CSU, CSLD, CSL, CSOT, DOVM, VMN)            \
  do {                                                                       \
    const char* bX = (const char*)smem + (((V)&1) << 14);                    \
    const char* bC = (const char*)smem + 32768 + (((V)&1) << 15);            \
    char* dX = (char*)smem + ((((V) + 1) & 1) << 14) + (w << 10);            \
    char* dC = (char*)smem + 32768 + (((V)&1) << 15) + (w << 10);            \
    i64x2 cfA[4], cfB[4], xA0, xB0, xA1, xB1;                                \
    if (CSLD) {                                                              \
      const float* _cp =                                                     \
          csq + ((((strip) << 3) + (CSOT)) << 8) + wc * 64 + (fq << 2);      \
      GLD4(CSL[0], _cp); GLD4(CSL[1], _cp + 16);                             \
      GLD4(CSL[2], _cp + 32); GLD4(CSL[3], _cp + 48);                        \
    }                                                                        \
    cfA[0] = RD(bC, rcb);          cfB[0] = RD(bC, rcbB);                    \
    cfA[1] = RD(bC, rcb + 2048);   cfB[1] = RD(bC, rcbB + 2048);             \
    cfA[2] = RD(bC, rcb + 4096);   cfB[2] = RD(bC, rcbB + 4096);             \
    cfA[3] = RD(bC, rcb + 6144);   cfB[3] = RD(bC, rcbB + 6144);             \
    xA0 = RD(bX, rxb);             xB0 = RD(bX, rxbB);                       \
    xA1 = RD(bX, rxb + 2048);      xB1 = RD(bX, rxbB + 2048);                \
    if ((V) + 1 < 32) {                                                      \
      async16(gx + XOFF((V) + 1, 0), dX);                                    \
      async16(gx + XOFF((V) + 1, 1), dX + 8192);                             \
    }                                                                        \
    LGKM0;                                                                   \
    __builtin_amdgcn_s_setprio(1);                                           \
    MF16(AN, 0, xA0, xB0, V);                                                \
    MF16(AN, 1, xA1, xB1, V);                                                \
    __builtin_amdgcn_s_setprio(0);                                           \
    BAR; /* all waves' cf reads of buf V&1 done -> C(V+2) may overwrite */   \
    xA0 = RD(bX, rxb + 4096);      xB0 = RD(bX, rxbB + 4096);                \
    xA1 = RD(bX, rxb + 6144);      xB1 = RD(bX, rxbB + 6144);                \
    if ((V) + 2 < 32) {                                                      \
      async16(gc + COFF((V) + 2, 0), dC);                                    \
      async16(gc + COFF((V) + 2, 1), dC + 8192);                             \
      async16(gc + COFF((V) + 2, 2), dC + 16384);                            \
      async16(gc + COFF((V) + 2, 3), dC + 24576);                            \
    }                                                                        \
    if (SEN) STFRAG4(AO, (V)&3, CSU, CPREO);                                 \
    LGKM0;                                                                   \
    __builtin_amdgcn_s_setprio(1);                                           \
    MF16(AN, 2, xA0, xB0, V);                                                \
    MF16(AN, 3, xA1, xB1, V);                                                \
    __builtin_amdgcn_s_setprio(0);                                           \
    if (DOVM) WAITVM(VMN);                                                   \
    BAR;                                                                     \
    __builtin_amdgcn_sched_barrier(0);                                       \
  } while (0)

  // --- prologue: xsr, C(0)x4 -> Cbuf0, X(0)x2 -> Xbuf0, C(1)x4 -> Cbuf1.
  // FIFO [xs4, C0x4, X0x2, C1x4] -> retire X0: vmcnt(4). ---
  {
    const float* xp = xsq + x0 + wr * 64 + fr;
    GLD1(xsr[0], xp); GLD1(xsr[1], xp + 16);
    GLD1(xsr[2], xp + 32); GLD1(xsr[3], xp + 48);
  }
  async16(gc + COFF(0, 0), (char*)smem + 32768 + (w << 10));
  async16(gc + COFF(0, 1), (char*)smem + 32768 + 8192 + (w << 10));
  async16(gc + COFF(0, 2), (char*)smem + 32768 + 16384 + (w << 10));
  async16(gc + COFF(0, 3), (char*)smem + 32768 + 24576 + (w << 10));
  async16(gx + XOFF(0, 0), (char*)smem + (w << 10));
  async16(gx + XOFF(0, 1), (char*)smem + 8192 + (w << 10));
  async16(gc + COFF(1, 0), (char*)smem + 65536 + (w << 10));
  async16(gc + COFF(1, 1), (char*)smem + 65536 + 8192 + (w << 10));
  async16(gc + COFF(1, 2), (char*)smem + 65536 + 16384 + (w << 10));
  async16(gc + COFF(1, 3), (char*)smem + 65536 + 24576 + (w << 10));
  WAITVM(4);
  BAR;
  __builtin_amdgcn_sched_barrier(0);

  // --- 32 K-tiles (8 output tiles), fully unrolled ---
  // ot0 (V0-3): fill aA, no stores; V2: csX <- cols 0
  KT(0, aA, aB, 0, CPI(0), csX, 0, csX, 0, 1, 4);
  KT(1, aA, aB, 0, CPI(0), csX, 0, csX, 0, 1, 4);
  KT(2, aA, aB, 0, CPI(0), csX, 1, csX, 0, 1, 4);
  KT(3, aA, aB, 0, CPI(0), csX, 0, csX, 0, 1, 4);
  // ot1 (V4-7): fill aB, store aA (cols 0, csX); V6: csY <- cols 1
  KT(4, aB, aA, 1, CPI(0), csX, 0, csY, 1, 1, 8);
  KT(5, aB, aA, 1, CPI(0), csX, 0, csY, 1, 1, 8);
  KT(6, aB, aA, 1, CPI(0), csX, 1, csY, 1, 1, 8);
  KT(7, aB, aA, 1, CPI(0), csX, 0, csY, 1, 1, 8);
  // ot2 (V8-11): fill aA, store aB (cols 1, csY); V10: csX <- cols 2
  KT(8, aA, aB, 1, CPI(1), csY, 0, csX, 2, 1, 8);
  KT(9, aA, aB, 1, CPI(1), csY, 0, csX, 2, 1, 8);
  KT(10, aA, aB, 1, CPI(1), csY, 1, csX, 2, 1, 8);
  KT(11, aA, aB, 1, CPI(1), csY, 0, csX, 2, 1, 8);
  // ot3 (V12-15): fill aB, store aA (cols 2, csX); V14: csY <- cols 3
  KT(12, aB, aA, 1, CPI(2), csX, 0, csY, 3, 1, 8);
  KT(13, aB, aA, 1, CPI(2), csX, 0, csY, 3, 1, 8);
  KT(14, aB, aA, 1, CPI(2), csX, 1, csY, 3, 1, 8);
  KT(15, aB, aA, 1, CPI(2), csX, 0, csY, 3, 1, 8);
  // ot4 (V16-19): fill aA, store aB (cols 3, csY); V18: csX <- cols 4
  KT(16, aA, aB, 1, CPI(3), csY, 0, csX, 4, 1, 8);
  KT(17, aA, aB, 1, CPI(3), csY, 0, csX, 4, 1, 8);
  KT(18, aA, aB, 1, CPI(3), csY, 1, csX, 4, 1, 8);
  KT(19, aA, aB, 1, CPI(3), csY, 0, csX, 4, 1, 8);
  // ot5 (V20-23): fill aB, store aA (cols 4, csX); V22: csY <- cols 5
  KT(20, aB, aA, 1, CPI(4), csX, 0, csY, 5, 1, 8);
  KT(21, aB, aA, 1, CPI(4), csX, 0, csY, 5, 1, 8);
  KT(22, aB, aA, 1, CPI(4), csX, 1, csY, 5, 1, 8);
  KT(23, aB, aA, 1, CPI(4), csX, 0, csY, 5, 1, 8);
  // ot6 (V24-27): fill aA, store aB (cols 5, csY); V26: csX <- cols 6
  KT(24, aA, aB, 1, CPI(5), csY, 0, csX, 6, 1, 8);
  KT(25, aA, aB, 1, CPI(5), csY, 0, csX, 6, 1, 8);
  KT(26, aA, aB, 1, CPI(5), csY, 1, csX, 6, 1, 8);
  KT(27, aA, aB, 1, CPI(5), csY, 0, csX, 6, 1, 8);
  // ot7 (V28-31): fill aB, store aA (cols 6, csX); V30: csY <- cols 7
  KT(28, aB, aA, 1, CPI(6), csX, 0, csY, 7, 1, 8);
  KT(29, aB, aA, 1, CPI(6), csX, 0, csY, 7, 1, 8);
  KT(30, aB, aA, 1, CPI(6), csX, 1, csY, 7, 1, 4);
  KT(31, aB, aA, 1, CPI(6), csX, 0, csY, 7, 0, 0);

  // --- tail: store aB (ot7 results, cols 7, csY loaded V30) ---
  STFRAG4(aB, 0, csY, CPI(7));
  STFRAG4(aB, 1, csY, CPI(7));
  STFRAG4(aB, 2, csY, CPI(7));
  STFRAG4(aB, 3, csY, CPI(7));
}

// ---------------------------------------------------------------------------
// Fallback (ws too small): direct tiled fp32 distance kernel.
// ---------------------------------------------------------------------------
__global__ void rbf_naive(const float* __restrict__ x,
                          const float* __restrict__ c,
                          float* __restrict__ out) {
  __shared__ float sx[16][17], sc[16][17];
  const int tx = threadIdx.x, ty = threadIdx.y;
  const int row = blockIdx.y * 16 + ty;
  const int colb = blockIdx.x * 16;
  float d = 0.f;
  for (int k0 = 0; k0 < DD; k0 += 16) {
    sx[ty][tx] = x[(size_t)row * DD + k0 + tx];
    sc[ty][tx] = c[(size_t)(colb + ty) * DD + k0 + tx];
    __syncthreads();
#pragma unroll
    for (int k = 0; k < 16; ++k) {
      float diff = sx[ty][k] - sc[tx][k];
      d += diff * diff;
    }
    __syncthreads();
  }
  out[(size_t)row * MM + colb + tx] = __expf(-d);
}

extern "C" void kernel_launch(void* const* d_in, const int* in_sizes, int n_in,
                              void* d_out, int out_size, void* d_ws,
                              size_t ws_size, hipStream_t stream) {
  const float* x = (const float*)d_in[0];
  const float* c = (const float*)d_in[1];
  float* out = (float*)d_out;

  char* ws = (char*)d_ws;
  unsigned char* x8 = (unsigned char*)ws;
  unsigned char* c8 = x8 + (size_t)NN * DD;
  float* xsq = (float*)(c8 + (size_t)MM * DD);
  float* csq = xsq + NN;
  const size_t need = (size_t)((char*)(csq + MM) - ws);

  if (ws_size < need) {
    dim3 grid(MM / 16, NN / 16), block(16, 16);
    rbf_naive<<<grid, block, 0, stream>>>(x, c, out);
    return;
  }

  prep_fp8<<<(NN + MM) / 4, 256, 0, stream>>>(x, c, x8, c8, xsq, csq);
  rbf_gemm<<<256, 512, 0, stream>>>(x8, c8, xsq, csq, out);
}

// Round 16
// 93.400 us; speedup vs baseline: 1.0339x; 1.0339x over previous
//
#include <hip/hip_runtime.h>
#include <hip/hip_bf16.h>

// RBF kernel layer: out[n][m] = exp(-||x_n - c_m||^2)
// N=16384, M=4096, D=512, fp32 in/out.
// Round 16: RESTORE r14 verbatim (93.2us, best). r15's 256-block persistent
// variant regressed (96.6): the 512-block 2-generation layout wins because
// gen-2's prologue staging overlaps gen-1's tail-store drain and finer
// blocks load-balance; a single long block exposes its tail serially.
//
// r14 = BK=128 persistent dual-bank fp8 GEMM:
// LDS 96KB: X[2][128][128B] @0/16384; C[2][256][128B] @32768/65536.
// Swizzle: LDS[row][slot] holds global 16B chunk g = slot ^ (row&7);
// read chunk fq at slot fq^(fr&7) (sxa), chunk fq|4 at (fq|4)^(fr&7) (sxb).
// Staging: linear dest (thread t -> row t>>3, slot t&7), source chunk
// (t&7)^((t>>3)&7). All LDS reads are direct typed derefs (r13 lesson:
// pointer->int->pointer round-trips defeat addrspace inference -> flat
// loads -> corrupt BOTH waitcnt domains -> broken vmcnt accounting).
// FIFO per tile V: [cs?x4, X(V+1)x2, C(V+2)x4, STx4]; boundary vmcnt:
// V0-3: 4; V4-13: 8; V14: 4; V15: none. Prologue [xs4, C0x4, X0x2, C1x4]
// -> vmcnt(4). acc banks alternate per ot; stores of old bank m-group V&3
// issued mid-tile (1-tile drain lease); grouped 4 n-frags back-to-back.

#define NN 16384
#define MM 4096
#define DD 512

typedef float f32x4 __attribute__((ext_vector_type(4)));
typedef long i64x2 __attribute__((ext_vector_type(2)));

__device__ __forceinline__ void async16(const void* g, void* l) {
  __builtin_amdgcn_global_load_lds(
      (const __attribute__((address_space(1))) void*)g,
      (__attribute__((address_space(3))) void*)l, 16, 0, 0);
}

#define MFMA8(a, b, c) __builtin_amdgcn_mfma_f32_16x16x32_fp8_fp8(a, b, c, 0, 0, 0)
#define WAITVM(n) asm volatile("s_waitcnt vmcnt(" #n ")" ::: "memory")
#define LGKM0 asm volatile("s_waitcnt lgkmcnt(0)" ::: "memory")
#define BAR __builtin_amdgcn_s_barrier()
#define GLD4(dst, addr) \
  asm volatile("global_load_dwordx4 %0, %1, off" : "=v"(dst) : "v"(addr))
#define GLD1(dst, addr) \
  asm volatile("global_load_dword %0, %1, off" : "=v"(dst) : "v"(addr))

// ---------------------------------------------------------------------------
// Prep: fp32 row -> fp8 e4m3 (row bytes packed (kt, fq)-major: byte =
// kt*64 + fq*16 + ks*8 + e for element k = kt*64 + ks*32 + fq*8 + e) +
// exact fp32 squared norm. One wave per row.
// ---------------------------------------------------------------------------
__global__ __launch_bounds__(256) void prep_fp8(
    const float* __restrict__ x, const float* __restrict__ c,
    unsigned char* __restrict__ x8, unsigned char* __restrict__ c8,
    float* __restrict__ xsq, float* __restrict__ csq) {
  const int w = threadIdx.x >> 6;
  const int lane = threadIdx.x & 63;
  int row = blockIdx.x * 4 + w;
  const float* src = x;
  unsigned char* dst = x8;
  float* sq = xsq;
  if (row >= NN) {
    row -= NN;
    src = c; dst = c8; sq = csq;
    if (row >= MM) return;
  }
  const float* p = src + (size_t)row * DD + lane * 8;
  float4 v0 = *(const float4*)p;
  float4 v1 = *(const float4*)(p + 4);
  float vv[8] = {v0.x, v0.y, v0.z, v0.w, v1.x, v1.y, v1.z, v1.w};
  float s = 0.f;
#pragma unroll
  for (int j = 0; j < 8; ++j) s += vv[j] * vv[j];
  int pk0 = __builtin_amdgcn_cvt_pk_fp8_f32(vv[0], vv[1], 0, false);
  int pk1 = __builtin_amdgcn_cvt_pk_fp8_f32(vv[2], vv[3], 0, false);
  int pk2 = __builtin_amdgcn_cvt_pk_fp8_f32(vv[4], vv[5], 0, false);
  int pk3 = __builtin_amdgcn_cvt_pk_fp8_f32(vv[6], vv[7], 0, false);
  uint2 wrd;
  wrd.x = (unsigned)(pk0 & 0xFFFF) | ((unsigned)pk1 << 16);
  wrd.y = (unsigned)(pk2 & 0xFFFF) | ((unsigned)pk3 << 16);
  const int db = ((lane >> 3) << 6) + ((lane & 3) << 4) + (((lane >> 2) & 1) << 3);
  *(uint2*)(dst + (size_t)row * DD + db) = wrd;
#pragma unroll
  for (int o = 32; o >= 1; o >>= 1) s += __shfl_down(s, o);
  if (lane == 0) sq[row] = s;
}

// ---------------------------------------------------------------------------
// Persistent GEMM. 512 blocks = 128 x-panels (BM=128) x 4 strips; 8 waves;
// per wave 64 x-rows (wr) x 64 c-cols (wc) = 4x4 16x16 frags; A=centroid,
// B=x (lane: x-row = fr, c-cols = fq*4+reg).
// ---------------------------------------------------------------------------
__global__ __launch_bounds__(512, 1) void rbf_gemm(
    const unsigned char* __restrict__ x8, const unsigned char* __restrict__ c8,
    const float* __restrict__ xsq, const float* __restrict__ csq,
    float* __restrict__ out) {
  __shared__ __attribute__((aligned(16))) unsigned char smem[98304];

  const int t = threadIdx.x;
  const int w = t >> 6;
  const int lane = t & 63;
  const int fr = lane & 15;
  const int fq = lane >> 4;
  const int wr = w >> 2;
  const int wc = w & 3;

  const int bid = blockIdx.x;
  const int a = bid & 7, qq = bid >> 3;
  const int x0 = ((a << 4) + (qq >> 2)) << 7;
  const int strip = qq & 3;

  // staging: thread t -> row t>>3 of 64-row issue, inverse-swizzled slot
  const int srow = t >> 3;
  const int ssl = ((t & 7) ^ ((t >> 3) & 7)) << 4;
  const unsigned char* gx = x8 + (size_t)(x0 + srow) * DD + ssl;
  const unsigned char* gc = c8 + (size_t)srow * DD + ssl;

#define XOFF(v, i) ((size_t)(i)*64 * DD + ((v)&3) * 128)
#define COFF(v, i)                                                   \
  ((size_t)(((((strip) << 2) + ((v) >> 2)) << 8) + (i)*64) * DD +    \
   ((v)&3) * 128)

  // ds_read slot offsets: chunk fq (kt0) at sxa, chunk fq|4 (kt1) at sxb
  const int sxa = (fq ^ (fr & 7)) << 4;
  const int sxb = ((fq | 4) ^ (fr & 7)) << 4;
  const int rowC = (wc * 64 + fr) * 128;
  const int rowX = (wr * 64 + fr) * 128;
  const int rcb = rowC + sxa, rcbB = rowC + sxb;   // + n*2048
  const int rxb = rowX + sxa, rxbB = rowX + sxb;   // + m*2048

  f32x4 aA[4][4], aB[4][4];
  f32x4 csX[4], csY[4];
  float xsr[4];

#define RD(base, off) (*(const i64x2*)((base) + (off)))

// one m-group: 4 n x 4 k-slices = 16 MFMAs. Zero-init acc at ot start.
#define MF16(AN, M, XA, XB, V)                                            \
  do {                                                                    \
    _Pragma("unroll") for (int _n = 0; _n < 4; ++_n) {                    \
      f32x4 _c = ((V)&3) == 0 ? (f32x4){0.f, 0.f, 0.f, 0.f} : AN[M][_n];  \
      _c = MFMA8(cfA[_n][0], XA[0], _c);                                  \
      _c = MFMA8(cfA[_n][1], XA[1], _c);                                  \
      _c = MFMA8(cfB[_n][0], XB[0], _c);                                  \
      AN[M][_n] = MFMA8(cfB[_n][1], XB[1], _c);                           \
    }                                                                     \
  } while (0)

// grouped store: 4 n-frags of m-group M, back-to-back (line merge)
#define STFRAG4(AO, M, CSU, CPREO)                                          \
  do {                                                                      \
    const float _xn = xsr[M] * -1.4426950408889634f;                        \
    float* _orow =                                                          \
        out + (size_t)(x0 + wr * 64 + (M)*16 + fr) * MM + (CPREO) +         \
        wc * 64 + (fq << 2);                                                \
    _Pragma("unroll") for (int _n = 0; _n < 4; ++_n) {                      \
      f32x4 _v;                                                             \
      _Pragma("unroll") for (int _j = 0; _j < 4; ++_j) {                    \
        float _arg = __builtin_fmaf(                                        \
            AO[M][_n][_j], 2.8853900817779268f,                             \
            __builtin_fmaf(CSU[_n][_j], -1.4426950408889634f, _xn));        \
        _v[_j] = fminf(__builtin_exp2f(_arg), 1.0f);                        \
      }                                                                     \
      *(f32x4*)(_orow + _n * 16) = _v;                                      \
    }                                                                       \
  } while (0)

#define KT(V, AN, AO, SEN, CPREO, CSU, CSLD, CSL, CSOT, DOVM, VMN)            \
  do {                                                                       \
    const char* bX = (const char*)smem + (((V)&1) << 14);                    \
    const char* bC = (const char*)smem + 32768 + (((V)&1) << 15);            \
    char* dX = (char*)smem + ((((V) + 1) & 1) << 14) + (w << 10);            \
    char* dC = (char*)smem + 32768 + (((V)&1) << 15) + (w << 10);            \
    i64x2 cfA[4], cfB[4], xA0, xB0, xA1, xB1;                                \
    if (CSLD) {                                                              \
      const float* _cp =                                                     \
          csq + ((((strip) << 2) + (CSOT)) << 8) + wc * 64 + (fq << 2);      \
      GLD4(CSL[0], _cp); GLD4(CSL[1], _cp + 16);                             \
      GLD4(CSL[2], _cp + 32); GLD4(CSL[3], _cp + 48);                        \
    }                                                                        \
    cfA[0] = RD(bC, rcb);          cfB[0] = RD(bC, rcbB);                    \
    cfA[1] = RD(bC, rcb + 2048);   cfB[1] = RD(bC, rcbB + 2048);             \
    cfA[2] = RD(bC, rcb + 4096);   cfB[2] = RD(bC, rcbB + 4096);             \
    cfA[3] = RD(bC, rcb + 6144);   cfB[3] = RD(bC, rcbB + 6144);             \
    xA0 = RD(bX, rxb);             xB0 = RD(bX, rxbB);                       \
    xA1 = RD(bX, rxb + 2048);      xB1 = RD(bX, rxbB + 2048);                \
    if ((V) + 1 < 16) {                                                      \
      async16(gx + XOFF((V) + 1, 0), dX);                                    \
      async16(gx + XOFF((V) + 1, 1), dX + 8192);                             \
    }                                                                        \
    LGKM0;                                                                   \
    __builtin_amdgcn_s_setprio(1);                                           \
    MF16(AN, 0, xA0, xB0, V);                                                \
    MF16(AN, 1, xA1, xB1, V);                                                \
    __builtin_amdgcn_s_setprio(0);                                           \
    BAR; /* all waves' cf reads of buf V&1 done -> C(V+2) may overwrite */   \
    xA0 = RD(bX, rxb + 4096);      xB0 = RD(bX, rxbB + 4096);                \
    xA1 = RD(bX, rxb + 6144);      xB1 = RD(bX, rxbB + 6144);                \
    if ((V) + 2 < 16) {                                                      \
      async16(gc + COFF((V) + 2, 0), dC);                                    \
      async16(gc + COFF((V) + 2, 1), dC + 8192);                             \
      async16(gc + COFF((V) + 2, 2), dC + 16384);                            \
      async16(gc + COFF((V) + 2, 3), dC + 24576);                            \
    }                                                                        \
    if (SEN) STFRAG4(AO, (V)&3, CSU, CPREO);                                 \
    LGKM0;                                                                   \
    __builtin_amdgcn_s_setprio(1);                                           \
    MF16(AN, 2, xA0, xB0, V);                                                \
    MF16(AN, 3, xA1, xB1, V);                                                \
    __builtin_amdgcn_s_setprio(0);                                           \
    if (DOVM) WAITVM(VMN);                                                   \
    BAR;                                                                     \
    __builtin_amdgcn_sched_barrier(0);                                       \
  } while (0)

  const int CP0 = ((strip << 2) + 0) << 8;
  const int CP1 = ((strip << 2) + 1) << 8;
  const int CP2 = ((strip << 2) + 2) << 8;
  const int CP3 = ((strip << 2) + 3) << 8;

  // --- prologue: xsr, C(0)x4 -> Cbuf0, X(0)x2 -> Xbuf0, C(1)x4 -> Cbuf1.
  // FIFO [xs4, C0x4, X0x2, C1x4] -> retire X0: vmcnt(4). ---
  {
    const float* xp = xsq + x0 + wr * 64 + fr;
    GLD1(xsr[0], xp); GLD1(xsr[1], xp + 16);
    GLD1(xsr[2], xp + 32); GLD1(xsr[3], xp + 48);
  }
  async16(gc + COFF(0, 0), (char*)smem + 32768 + (w << 10));
  async16(gc + COFF(0, 1), (char*)smem + 32768 + 8192 + (w << 10));
  async16(gc + COFF(0, 2), (char*)smem + 32768 + 16384 + (w << 10));
  async16(gc + COFF(0, 3), (char*)smem + 32768 + 24576 + (w << 10));
  async16(gx + XOFF(0, 0), (char*)smem + (w << 10));
  async16(gx + XOFF(0, 1), (char*)smem + 8192 + (w << 10));
  async16(gc + COFF(1, 0), (char*)smem + 65536 + (w << 10));
  async16(gc + COFF(1, 1), (char*)smem + 65536 + 8192 + (w << 10));
  async16(gc + COFF(1, 2), (char*)smem + 65536 + 16384 + (w << 10));
  async16(gc + COFF(1, 3), (char*)smem + 65536 + 24576 + (w << 10));
  WAITVM(4);
  BAR;
  __builtin_amdgcn_sched_barrier(0);

  // --- 16 K-tiles, fully unrolled ---
  // ot0 (V0-3): fill aA, no stores; V2: csX <- CP0
  KT(0, aA, aB, 0, CP0, csX, 0, csX, 0, 1, 4);
  KT(1, aA, aB, 0, CP0, csX, 0, csX, 0, 1, 4);
  KT(2, aA, aB, 0, CP0, csX, 1, csX, 0, 1, 4);
  KT(3, aA, aB, 0, CP0, csX, 0, csX, 0, 1, 4);
  // ot1 (V4-7): fill aB, store aA (CP0, csX); V6: csY <- CP1
  KT(4, aB, aA, 1, CP0, csX, 0, csY, 1, 1, 8);
  KT(5, aB, aA, 1, CP0, csX, 0, csY, 1, 1, 8);
  KT(6, aB, aA, 1, CP0, csX, 1, csY, 1, 1, 8);
  KT(7, aB, aA, 1, CP0, csX, 0, csY, 1, 1, 8);
  // ot2 (V8-11): fill aA, store aB (CP1, csY); V10: csX <- CP2
  KT(8, aA, aB, 1, CP1, csY, 0, csX, 2, 1, 8);
  KT(9, aA, aB, 1, CP1, csY, 0, csX, 2, 1, 8);
  KT(10, aA, aB, 1, CP1, csY, 1, csX, 2, 1, 8);
  KT(11, aA, aB, 1, CP1, csY, 0, csX, 2, 1, 8);
  // ot3 (V12-15): fill aB, store aA (CP2, csX); V14: csY <- CP3
  KT(12, aB, aA, 1, CP2, csX, 0, csY, 3, 1, 8);
  KT(13, aB, aA, 1, CP2, csX, 0, csY, 3, 1, 8);
  KT(14, aB, aA, 1, CP2, csX, 1, csY, 3, 1, 4);
  KT(15, aB, aA, 1, CP2, csX, 0, csY, 3, 0, 0);

  // --- tail: store aB (ot3 results, CP3, csY) ---
  STFRAG4(aB, 0, csY, CP3);
  STFRAG4(aB, 1, csY, CP3);
  STFRAG4(aB, 2, csY, CP3);
  STFRAG4(aB, 3, csY, CP3);
}

// ---------------------------------------------------------------------------
// Fallback (ws too small): direct tiled fp32 distance kernel.
// ---------------------------------------------------------------------------
__global__ void rbf_naive(const float* __restrict__ x,
                          const float* __restrict__ c,
                          float* __restrict__ out) {
  __shared__ float sx[16][17], sc[16][17];
  const int tx = threadIdx.x, ty = threadIdx.y;
  const int row = blockIdx.y * 16 + ty;
  const int colb = blockIdx.x * 16;
  float d = 0.f;
  for (int k0 = 0; k0 < DD; k0 += 16) {
    sx[ty][tx] = x[(size_t)row * DD + k0 + tx];
    sc[ty][tx] = c[(size_t)(colb + ty) * DD + k0 + tx];
    __syncthreads();
#pragma unroll
    for (int k = 0; k < 16; ++k) {
      float diff = sx[ty][k] - sc[tx][k];
      d += diff * diff;
    }
    __syncthreads();
  }
  out[(size_t)row * MM + colb + tx] = __expf(-d);
}

extern "C" void kernel_launch(void* const* d_in, const int* in_sizes, int n_in,
                              void* d_out, int out_size, void* d_ws,
                              size_t ws_size, hipStream_t stream) {
  const float* x = (const float*)d_in[0];
  const float* c = (const float*)d_in[1];
  float* out = (float*)d_out;

  char* ws = (char*)d_ws;
  unsigned char* x8 = (unsigned char*)ws;
  unsigned char* c8 = x8 + (size_t)NN * DD;
  float* xsq = (float*)(c8 + (size_t)MM * DD);
  float* csq = xsq + NN;
  const size_t need = (size_t)((char*)(csq + MM) - ws);

  if (ws_size < need) {
    dim3 grid(MM / 16, NN / 16), block(16, 16);
    rbf_naive<<<grid, block, 0, stream>>>(x, c, out);
    return;
  }

  prep_fp8<<<(NN + MM) / 4, 256, 0, stream>>>(x, c, x8, c8, xsq, csq);
  rbf_gemm<<<512, 512, 0, stream>>>(x8, c8, xsq, csq, out);
}

// Round 17
// 93.202 us; speedup vs baseline: 1.0361x; 1.0021x over previous
//
#include <hip/hip_runtime.h>
#include <hip/hip_bf16.h>

// RBF kernel layer: out[n][m] = exp(-||x_n - c_m||^2)
// N=16384, M=4096, D=512, fp32 in/out.
// Round 17: r14 (93.2us best) + 3-DEEP staging buffers to double the store
// drain lease. In-order vmcnt retirement means the boundary wait for
// X(V+1) force-drains all older stores; with 2-deep bufs that is a 1-tile
// (~2.5us) lease, and all 256 CUs burst in phase. 3-deep X (48KB) + 3-deep
// C (96KB) = 144KB LDS; X(V+1) is staged a full tile earlier, so the
// boundary wait relaxes to vmcnt(18/22) and stores get a 2-tile lease.
//
// Schedule per tile V (else identical to r14):
//   start: cs?x4 (GLD4), cf/x ds_reads, stage X(V+2) -> Xbuf (V+2)%3
//          [X(V-1)'s buf, fully read by end of tile V-1]
//   BAR-mid; stage C(V+3)x4 -> Cbuf (V+3)%3 == V%3 [cf reads done]; STx4
//   end: WAITVM(N) + BAR.
// Boundary needs X(V+1) (staged tile V-1 start) + C(V+1) (staged tile V-2,
// FIFO-older) retired. N = #items issued after X(V+1):
//   V-1 tail: C(V+2)x4, ST(V-1)x4?; tile V: cs?x4, X(V+2)x2?, C(V+3)x4?,
//   ST(V)x4?  ->  V0:10 V1:10 V2:14 V3:10 V4:14 V5:18 V6:22 V7:18 V8:18
//   V9:18 V10:22 V11:18 V12:18 V13:14 V14:12 V15:none.
// Prologue FIFO [xs4, C0x4, X0x2, C1x4, X1x2, C2x4] -> retire X0: vmcnt(10).
// All LDS reads direct typed derefs (r13 lesson: int round-trips -> flat
// loads -> corrupt both waitcnt domains).

#define NN 16384
#define MM 4096
#define DD 512

typedef float f32x4 __attribute__((ext_vector_type(4)));
typedef long i64x2 __attribute__((ext_vector_type(2)));

__device__ __forceinline__ void async16(const void* g, void* l) {
  __builtin_amdgcn_global_load_lds(
      (const __attribute__((address_space(1))) void*)g,
      (__attribute__((address_space(3))) void*)l, 16, 0, 0);
}

#define MFMA8(a, b, c) __builtin_amdgcn_mfma_f32_16x16x32_fp8_fp8(a, b, c, 0, 0, 0)
#define WAITVM(n) asm volatile("s_waitcnt vmcnt(" #n ")" ::: "memory")
#define LGKM0 asm volatile("s_waitcnt lgkmcnt(0)" ::: "memory")
#define BAR __builtin_amdgcn_s_barrier()
#define GLD4(dst, addr) \
  asm volatile("global_load_dwordx4 %0, %1, off" : "=v"(dst) : "v"(addr))
#define GLD1(dst, addr) \
  asm volatile("global_load_dword %0, %1, off" : "=v"(dst) : "v"(addr))

// ---------------------------------------------------------------------------
// Prep: fp32 row -> fp8 e4m3 (row bytes packed (kt, fq)-major: byte =
// kt*64 + fq*16 + ks*8 + e for element k = kt*64 + ks*32 + fq*8 + e) +
// exact fp32 squared norm. One wave per row.
// ---------------------------------------------------------------------------
__global__ __launch_bounds__(256) void prep_fp8(
    const float* __restrict__ x, const float* __restrict__ c,
    unsigned char* __restrict__ x8, unsigned char* __restrict__ c8,
    float* __restrict__ xsq, float* __restrict__ csq) {
  const int w = threadIdx.x >> 6;
  const int lane = threadIdx.x & 63;
  int row = blockIdx.x * 4 + w;
  const float* src = x;
  unsigned char* dst = x8;
  float* sq = xsq;
  if (row >= NN) {
    row -= NN;
    src = c; dst = c8; sq = csq;
    if (row >= MM) return;
  }
  const float* p = src + (size_t)row * DD + lane * 8;
  float4 v0 = *(const float4*)p;
  float4 v1 = *(const float4*)(p + 4);
  float vv[8] = {v0.x, v0.y, v0.z, v0.w, v1.x, v1.y, v1.z, v1.w};
  float s = 0.f;
#pragma unroll
  for (int j = 0; j < 8; ++j) s += vv[j] * vv[j];
  int pk0 = __builtin_amdgcn_cvt_pk_fp8_f32(vv[0], vv[1], 0, false);
  int pk1 = __builtin_amdgcn_cvt_pk_fp8_f32(vv[2], vv[3], 0, false);
  int pk2 = __builtin_amdgcn_cvt_pk_fp8_f32(vv[4], vv[5], 0, false);
  int pk3 = __builtin_amdgcn_cvt_pk_fp8_f32(vv[6], vv[7], 0, false);
  uint2 wrd;
  wrd.x = (unsigned)(pk0 & 0xFFFF) | ((unsigned)pk1 << 16);
  wrd.y = (unsigned)(pk2 & 0xFFFF) | ((unsigned)pk3 << 16);
  const int db = ((lane >> 3) << 6) + ((lane & 3) << 4) + (((lane >> 2) & 1) << 3);
  *(uint2*)(dst + (size_t)row * DD + db) = wrd;
#pragma unroll
  for (int o = 32; o >= 1; o >>= 1) s += __shfl_down(s, o);
  if (lane == 0) sq[row] = s;
}

// ---------------------------------------------------------------------------
// Persistent GEMM. 512 blocks = 128 x-panels (BM=128) x 4 strips; 8 waves;
// per wave 64 x-rows (wr) x 64 c-cols (wc) = 4x4 16x16 frags; A=centroid,
// B=x (lane: x-row = fr, c-cols = fq*4+reg).
// LDS 144KB: X[3][128][128B] @0/16384/32768; C[3][256][128B] @49152+k*32768.
// Swizzle: LDS[row][slot] holds global 16B chunk g = slot ^ (row&7);
// read chunk fq at slot fq^(fr&7) (sxa), chunk fq|4 at (fq|4)^(fr&7) (sxb).
// Staging: linear dest (thread t -> row t>>3, slot t&7), source chunk
// (t&7)^((t>>3)&7).
// ---------------------------------------------------------------------------
__global__ __launch_bounds__(512, 1) void rbf_gemm(
    const unsigned char* __restrict__ x8, const unsigned char* __restrict__ c8,
    const float* __restrict__ xsq, const float* __restrict__ csq,
    float* __restrict__ out) {
  __shared__ __attribute__((aligned(16))) unsigned char smem[147456];

  const int t = threadIdx.x;
  const int w = t >> 6;
  const int lane = t & 63;
  const int fr = lane & 15;
  const int fq = lane >> 4;
  const int wr = w >> 2;
  const int wc = w & 3;

  const int bid = blockIdx.x;
  const int a = bid & 7, qq = bid >> 3;
  const int x0 = ((a << 4) + (qq >> 2)) << 7;
  const int strip = qq & 3;

  // staging: thread t -> row t>>3 of 64-row issue, inverse-swizzled slot
  const int srow = t >> 3;
  const int ssl = ((t & 7) ^ ((t >> 3) & 7)) << 4;
  const unsigned char* gx = x8 + (size_t)(x0 + srow) * DD + ssl;
  const unsigned char* gc = c8 + (size_t)srow * DD + ssl;

#define XOFF(v, i) ((size_t)(i)*64 * DD + ((v)&3) * 128)
#define COFF(v, i)                                                   \
  ((size_t)(((((strip) << 2) + ((v) >> 2)) << 8) + (i)*64) * DD +    \
   ((v)&3) * 128)

  // ds_read slot offsets: chunk fq (kt0) at sxa, chunk fq|4 (kt1) at sxb
  const int sxa = (fq ^ (fr & 7)) << 4;
  const int sxb = ((fq | 4) ^ (fr & 7)) << 4;
  const int rowC = (wc * 64 + fr) * 128;
  const int rowX = (wr * 64 + fr) * 128;
  const int rcb = rowC + sxa, rcbB = rowC + sxb;   // + n*2048
  const int rxb = rowX + sxa, rxbB = rowX + sxb;   // + m*2048

  f32x4 aA[4][4], aB[4][4];
  f32x4 csX[4], csY[4];
  float xsr[4];

#define RD(base, off) (*(const i64x2*)((base) + (off)))

// one m-group: 4 n x 4 k-slices = 16 MFMAs. Zero-init acc at ot start.
#define MF16(AN, M, XA, XB, V)                                            \
  do {                                                                    \
    _Pragma("unroll") for (int _n = 0; _n < 4; ++_n) {                    \
      f32x4 _c = ((V)&3) == 0 ? (f32x4){0.f, 0.f, 0.f, 0.f} : AN[M][_n];  \
      _c = MFMA8(cfA[_n][0], XA[0], _c);                                  \
      _c = MFMA8(cfA[_n][1], XA[1], _c);                                  \
      _c = MFMA8(cfB[_n][0], XB[0], _c);                                  \
      AN[M][_n] = MFMA8(cfB[_n][1], XB[1], _c);                           \
    }                                                                     \
  } while (0)

// grouped store: 4 n-frags of m-group M, back-to-back (line merge)
#define STFRAG4(AO, M, CSU, CPREO)                                          \
  do {                                                                      \
    const float _xn = xsr[M] * -1.4426950408889634f;                        \
    float* _orow =                                                          \
        out + (size_t)(x0 + wr * 64 + (M)*16 + fr) * MM + (CPREO) +         \
        wc * 64 + (fq << 2);                                                \
    _Pragma("unroll") for (int _n = 0; _n < 4; ++_n) {                      \
      f32x4 _v;                                                             \
      _Pragma("unroll") for (int _j = 0; _j < 4; ++_j) {                    \
        float _arg = __builtin_fmaf(                                        \
            AO[M][_n][_j], 2.8853900817779268f,                             \
            __builtin_fmaf(CSU[_n][_j], -1.4426950408889634f, _xn));        \
        _v[_j] = fminf(__builtin_exp2f(_arg), 1.0f);                        \
      }                                                                     \
      *(f32x4*)(_orow + _n * 16) = _v;                                      \
    }                                                                       \
  } while (0)

// KT: one K-tile. X read buf V%3, staged (V+2)%3; C read buf V%3, staged
// C(V+3) -> (V+3)%3 == V%3 after BAR-mid (cf reads done).
#define KT(V, AN, AO, SEN, CPREO, CSU, CSLD, CSL, CSOT, DOVM, VMN)            \
  do {                                                                       \
    const char* bX = (const char*)smem + ((((V) % 3)) << 14);                \
    const char* bC = (const char*)smem + 49152 + ((((V) % 3)) << 15);        \
    char* dX = (char*)smem + ((((V) + 2) % 3) << 14) + (w << 10);            \
    char* dC = (char*)smem + 49152 + ((((V) + 3) % 3) << 15) + (w << 10);    \
    i64x2 cfA[4], cfB[4], xA0, xB0, xA1, xB1;                                \
    if (CSLD) {                                                              \
      const float* _cp =                                                     \
          csq + ((((strip) << 2) + (CSOT)) << 8) + wc * 64 + (fq << 2);      \
      GLD4(CSL[0], _cp); GLD4(CSL[1], _cp + 16);                             \
      GLD4(CSL[2], _cp + 32); GLD4(CSL[3], _cp + 48);                        \
    }                                                                        \
    cfA[0] = RD(bC, rcb);          cfB[0] = RD(bC, rcbB);                    \
    cfA[1] = RD(bC, rcb + 2048);   cfB[1] = RD(bC, rcbB + 2048);             \
    cfA[2] = RD(bC, rcb + 4096);   cfB[2] = RD(bC, rcbB + 4096);             \
    cfA[3] = RD(bC, rcb + 6144);   cfB[3] = RD(bC, rcbB + 6144);             \
    xA0 = RD(bX, rxb);             xB0 = RD(bX, rxbB);                       \
    xA1 = RD(bX, rxb + 2048);      xB1 = RD(bX, rxbB + 2048);                \
    if ((V) + 2 < 16) {                                                      \
      async16(gx + XOFF((V) + 2, 0), dX);                                    \
      async16(gx + XOFF((V) + 2, 1), dX + 8192);                             \
    }                                                                        \
    LGKM0;                                                                   \
    __builtin_amdgcn_s_setprio(1);                                           \
    MF16(AN, 0, xA0, xB0, V);                                                \
    MF16(AN, 1, xA1, xB1, V);                                                \
    __builtin_amdgcn_s_setprio(0);                                           \
    BAR; /* all waves' cf reads of buf V%3 done -> C(V+3) may overwrite */   \
    xA0 = RD(bX, rxb + 4096);      xB0 = RD(bX, rxbB + 4096);                \
    xA1 = RD(bX, rxb + 6144);      xB1 = RD(bX, rxbB + 6144);                \
    if ((V) + 3 < 16) {                                                      \
      async16(gc + COFF((V) + 3, 0), dC);                                    \
      async16(gc + COFF((V) + 3, 1), dC + 8192);                             \
      async16(gc + COFF((V) + 3, 2), dC + 16384);                            \
      async16(gc + COFF((V) + 3, 3), dC + 24576);                            \
    }                                                                        \
    if (SEN) STFRAG4(AO, (V)&3, CSU, CPREO);                                 \
    LGKM0;                                                                   \
    __builtin_amdgcn_s_setprio(1);                                           \
    MF16(AN, 2, xA0, xB0, V);                                                \
    MF16(AN, 3, xA1, xB1, V);                                                \
    __builtin_amdgcn_s_setprio(0);                                           \
    if (DOVM) WAITVM(VMN);                                                   \
    BAR;                                                                     \
    __builtin_amdgcn_sched_barrier(0);                                       \
  } while (0)

  const int CP0 = ((strip << 2) + 0) << 8;
  const int CP1 = ((strip << 2) + 1) << 8;
  const int CP2 = ((strip << 2) + 2) << 8;
  const int CP3 = ((strip << 2) + 3) << 8;

  // --- prologue: xsr, then C(0)x4 -> Cbuf0, X(0)x2 -> Xbuf0,
  // C(1)x4 -> Cbuf1, X(1)x2 -> Xbuf1, C(2)x4 -> Cbuf2.
  // FIFO [xs4, C0x4, X0x2, C1x4, X1x2, C2x4] -> retire X0: vmcnt(10). ---
  {
    const float* xp = xsq + x0 + wr * 64 + fr;
    GLD1(xsr[0], xp); GLD1(xsr[1], xp + 16);
    GLD1(xsr[2], xp + 32); GLD1(xsr[3], xp + 48);
  }
  async16(gc + COFF(0, 0), (char*)smem + 49152 + (w << 10));
  async16(gc + COFF(0, 1), (char*)smem + 49152 + 8192 + (w << 10));
  async16(gc + COFF(0, 2), (char*)smem + 49152 + 16384 + (w << 10));
  async16(gc + COFF(0, 3), (char*)smem + 49152 + 24576 + (w << 10));
  async16(gx + XOFF(0, 0), (char*)smem + (w << 10));
  async16(gx + XOFF(0, 1), (char*)smem + 8192 + (w << 10));
  async16(gc + COFF(1, 0), (char*)smem + 81920 + (w << 10));
  async16(gc + COFF(1, 1), (char*)smem + 81920 + 8192 + (w << 10));
  async16(gc + COFF(1, 2), (char*)smem + 81920 + 16384 + (w << 10));
  async16(gc + COFF(1, 3), (char*)smem + 81920 + 24576 + (w << 10));
  async16(gx + XOFF(1, 0), (char*)smem + 16384 + (w << 10));
  async16(gx + XOFF(1, 1), (char*)smem + 16384 + 8192 + (w << 10));
  async16(gc + COFF(2, 0), (char*)smem + 114688 + (w << 10));
  async16(gc + COFF(2, 1), (char*)smem + 114688 + 8192 + (w << 10));
  async16(gc + COFF(2, 2), (char*)smem + 114688 + 16384 + (w << 10));
  async16(gc + COFF(2, 3), (char*)smem + 114688 + 24576 + (w << 10));
  WAITVM(10);
  BAR;
  __builtin_amdgcn_sched_barrier(0);

  // --- 16 K-tiles, fully unrolled; boundary N per the FIFO table ---
  // ot0 (V0-3): fill aA, no stores; V2: csX <- CP0
  KT(0, aA, aB, 0, CP0, csX, 0, csX, 0, 1, 10);
  KT(1, aA, aB, 0, CP0, csX, 0, csX, 0, 1, 10);
  KT(2, aA, aB, 0, CP0, csX, 1, csX, 0, 1, 14);
  KT(3, aA, aB, 0, CP0, csX, 0, csX, 0, 1, 10);
  // ot1 (V4-7): fill aB, store aA (CP0, csX); V6: csY <- CP1
  KT(4, aB, aA, 1, CP0, csX, 0, csY, 1, 1, 14);
  KT(5, aB, aA, 1, CP0, csX, 0, csY, 1, 1, 18);
  KT(6, aB, aA, 1, CP0, csX, 1, csY, 1, 1, 22);
  KT(7, aB, aA, 1, CP0, csX, 0, csY, 1, 1, 18);
  // ot2 (V8-11): fill aA, store aB (CP1, csY); V10: csX <- CP2
  KT(8, aA, aB, 1, CP1, csY, 0, csX, 2, 1, 18);
  KT(9, aA, aB, 1, CP1, csY, 0, csX, 2, 1, 18);
  KT(10, aA, aB, 1, CP1, csY, 1, csX, 2, 1, 22);
  KT(11, aA, aB, 1, CP1, csY, 0, csX, 2, 1, 18);
  // ot3 (V12-15): fill aB, store aA (CP2, csX); V14: csY <- CP3
  KT(12, aB, aA, 1, CP2, csX, 0, csY, 3, 1, 18);
  KT(13, aB, aA, 1, CP2, csX, 0, csY, 3, 1, 14);
  KT(14, aB, aA, 1, CP2, csX, 1, csY, 3, 1, 12);
  KT(15, aB, aA, 1, CP2, csX, 0, csY, 3, 0, 0);

  // --- tail: store aB (ot3 results, CP3, csY) ---
  STFRAG4(aB, 0, csY, CP3);
  STFRAG4(aB, 1, csY, CP3);
  STFRAG4(aB, 2, csY, CP3);
  STFRAG4(aB, 3, csY, CP3);
}

// ---------------------------------------------------------------------------
// Fallback (ws too small): direct tiled fp32 distance kernel.
// ---------------------------------------------------------------------------
__global__ void rbf_naive(const float* __restrict__ x,
                          const float* __restrict__ c,
                          float* __restrict__ out) {
  __shared__ float sx[16][17], sc[16][17];
  const int tx = threadIdx.x, ty = threadIdx.y;
  const int row = blockIdx.y * 16 + ty;
  const int colb = blockIdx.x * 16;
  float d = 0.f;
  for (int k0 = 0; k0 < DD; k0 += 16) {
    sx[ty][tx] = x[(size_t)row * DD + k0 + tx];
    sc[ty][tx] = c[(size_t)(colb + ty) * DD + k0 + tx];
    __syncthreads();
#pragma unroll
    for (int k = 0; k < 16; ++k) {
      float diff = sx[ty][k] - sc[tx][k];
      d += diff * diff;
    }
    __syncthreads();
  }
  out[(size_t)row * MM + colb + tx] = __expf(-d);
}

extern "C" void kernel_launch(void* const* d_in, const int* in_sizes, int n_in,
                              void* d_out, int out_size, void* d_ws,
                              size_t ws_size, hipStream_t stream) {
  const float* x = (const float*)d_in[0];
  const float* c = (const float*)d_in[1];
  float* out = (float*)d_out;

  char* ws = (char*)d_ws;
  unsigned char* x8 = (unsigned char*)ws;
  unsigned char* c8 = x8 + (size_t)NN * DD;
  float* xsq = (float*)(c8 + (size_t)MM * DD);
  float* csq = xsq + NN;
  const size_t need = (size_t)((char*)(csq + MM) - ws);

  if (ws_size < need) {
    dim3 grid(MM / 16, NN / 16), block(16, 16);
    rbf_naive<<<grid, block, 0, stream>>>(x, c, out);
    return;
  }

  prep_fp8<<<(NN + MM) / 4, 256, 0, stream>>>(x, c, x8, c8, xsq, csq);
  rbf_gemm<<<512, 512, 0, stream>>>(x8, c8, xsq, csq, out);
}